// Round 6
// baseline (509.551 us; speedup 1.0000x reference)
//
#include <hip/hip_runtime.h>
#include <hip/hip_bf16.h>

#define N      4096
#define NFEAT  512
#define NHID   64
#define NHEADS 8
#define NCLASS 40
#define ALPHA  0.2f
#define LOG2E  1.44269504f

typedef unsigned short u16;
typedef unsigned int   u32;
typedef __attribute__((ext_vector_type(8))) short bf16x8;
typedef __attribute__((ext_vector_type(4))) float f32x4;

// bf16 bits -> f32
__device__ __forceinline__ float b2f(u16 u) {
    return __uint_as_float(((u32)u) << 16);
}
// RNE-rounded value kept in HIGH 16 bits (no shift; perm extracts)
__device__ __forceinline__ u32 rnd_hi(float f) {
    u32 u = __float_as_uint(f);
    return u + 0x7FFFu + ((u >> 16) & 1u);
}
// pack two f32 -> two bf16 in one u32 (lo = first arg) via v_perm_b32
__device__ __forceinline__ u32 pkbf(float lo, float hi) {
    return __builtin_amdgcn_perm(rnd_hi(hi), rnd_hi(lo), 0x07060302);
}
// single f32 -> bf16 bits (RNE)
__device__ __forceinline__ u16 f2b(float f) {
    return (u16)(rnd_hi(f) >> 16);
}

// ---------------- KCX: x f32 -> xb bf16 (same layout) ---------------------------
__global__ __launch_bounds__(256) void kcx(const float* __restrict__ x,
                                           u16* __restrict__ xb) {
    const int g = blockIdx.x * 256 + threadIdx.x;       // 262144 threads x 8 elems
    const size_t base = (size_t)g * 8;
    float4 v0 = *(const float4*)&x[base];
    float4 v1 = *(const float4*)&x[base + 4];
    uint4 o;
    o.x = pkbf(v0.x, v0.y); o.y = pkbf(v0.z, v0.w);
    o.z = pkbf(v1.x, v1.y); o.w = pkbf(v1.z, v1.w);
    *(uint4*)&xb[base] = o;
}

// ---------------- KCW: W1 [h][f][d] f32 -> W1b bf16 [h][d][f] -------------------
__global__ __launch_bounds__(256) void kcw(const float* __restrict__ W1,
                                           u16* __restrict__ W1b) {
    __shared__ float ts[64 * 68];   // [f-local][d], pitch 68
    const int t  = threadIdx.x;
    const int f0 = blockIdx.x * 64;
    const int h  = blockIdx.y;
    #pragma unroll
    for (int i = 0; i < 4; ++i) {
        int flat = t + 256 * i;
        int row = flat >> 4;                    // f-local
        int c4  = (flat & 15) * 4;              // d
        *(float4*)&ts[row * 68 + c4] =
            *(const float4*)&W1[((size_t)h * 512 + f0 + row) * 64 + c4];
    }
    __syncthreads();
    const int d  = t >> 2;
    const int fs = (t & 3) * 16;
    u32 p[8];
    #pragma unroll
    for (int j = 0; j < 8; ++j)
        p[j] = pkbf(ts[(fs + 2 * j) * 68 + d], ts[(fs + 2 * j + 1) * 68 + d]);
    u32* dst = (u32*)&W1b[((size_t)(h * 64 + d)) * 512 + f0 + fs];
    *(uint4*)dst       = make_uint4(p[0], p[1], p[2], p[3]);
    *(uint4*)(dst + 4) = make_uint4(p[4], p[5], p[6], p[7]);
}

// ---------------- K1M: Wh1T[h][d][n] = bf16( sum_f xb[n,f] * W1b[h,d,f] ) -------
// grid (64 n-tiles, 8 heads) x 256; MFMA 16x16x32, writes transposed bf16 directly.
__global__ __launch_bounds__(256, 4) void k1m_gemm1(const u16* __restrict__ xb,
                                                    const u16* __restrict__ W1b,
                                                    u16* __restrict__ Wh1T) {
    __shared__ u16 xs[64 * 72];    // [n-local][f-chunk], pitch 72
    __shared__ u16 wvs[64 * 72];   // [d][f-chunk]
    const int t    = threadIdx.x;
    const int n0   = blockIdx.x * 64;
    const int h    = blockIdx.y;
    const int lane = t & 63;
    const int l15  = lane & 15;
    const int q    = lane >> 4;
    const int wrow = (t >> 6) * 16;
    f32x4 acc[4];
    #pragma unroll
    for (int df = 0; df < 4; ++df)
        #pragma unroll
        for (int r = 0; r < 4; ++r) acc[df][r] = 0.f;
    for (int f0 = 0; f0 < 512; f0 += 64) {
        uint4 sx[2], sw[2];
        #pragma unroll
        for (int i = 0; i < 2; ++i) {
            int flat = t + 256 * i;
            int row = flat >> 3;
            int c8  = (flat & 7) * 8;
            sx[i] = *(const uint4*)&xb[(size_t)(n0 + row) * 512 + f0 + c8];
            sw[i] = *(const uint4*)&W1b[((size_t)(h * 64 + row)) * 512 + f0 + c8];
        }
        __syncthreads();
        #pragma unroll
        for (int i = 0; i < 2; ++i) {
            int flat = t + 256 * i;
            int row = flat >> 3;
            int c8  = (flat & 7) * 8;
            *(uint4*)&xs[row * 72 + c8]  = sx[i];
            *(uint4*)&wvs[row * 72 + c8] = sw[i];
        }
        __syncthreads();
        #pragma unroll
        for (int ks = 0; ks < 2; ++ks) {
            int k0 = ks * 32 + q * 8;
            bf16x8 a = *(const bf16x8*)&xs[(wrow + l15) * 72 + k0];
            #pragma unroll
            for (int df = 0; df < 4; ++df) {
                bf16x8 b = *(const bf16x8*)&wvs[(df * 16 + l15) * 72 + k0];
                acc[df] = __builtin_amdgcn_mfma_f32_16x16x32_bf16(a, b, acc[df], 0, 0, 0);
            }
        }
    }
    // C row = q*4 + r (n-local), col = l15 (d-local); pack 4 consecutive n as bf16
    #pragma unroll
    for (int df = 0; df < 4; ++df) {
        uint2 o;
        o.x = pkbf(acc[df][0], acc[df][1]);
        o.y = pkbf(acc[df][2], acc[df][3]);
        *(uint2*)&Wh1T[((size_t)(h * 64 + df * 16 + l15)) * 4096 + n0 + wrow + q * 4] = o;
    }
}

// ---------------- K2: F1/F2 (pre-scaled by log2e) from Wh1T bf16 ----------------
__global__ __launch_bounds__(256) void k2_f12(const u16* __restrict__ Wh1T,
                                              const float* __restrict__ a1,
                                              float* __restrict__ F1,
                                              float* __restrict__ F2) {
    const int g = blockIdx.x * 256 + threadIdx.x;   // 32768 threads
    const int h = g >> 12;
    const int n = g & 4095;
    float s1 = 0.f, s2 = 0.f;
    #pragma unroll 8
    for (int d = 0; d < 64; ++d) {
        float v = b2f(Wh1T[((size_t)(h * 64 + d)) * 4096 + n]);
        s1 += v * a1[h * 128 + d];
        s2 += v * a1[h * 128 + 64 + d];
    }
    F1[h * 4096 + n] = s1 * LOG2E;
    F2[h * 4096 + n] = s2 * LOG2E;
}

// ---------------- K3: layer-1 attention partials; A-frags in registers ----------
// grid (64 n-tiles, 8 heads, 2 m-chunks) x 256. LDS = B-tile only (21.8 KB).
// w = exp2(max(t, 0.2t)) with t = (f1+f2)*log2e; masked by adj.
__global__ __launch_bounds__(256, 5) void k3_attn1(const int* __restrict__ adj1,
                                                   const u16* __restrict__ Wh1T,
                                                   const float* __restrict__ F1,
                                                   const float* __restrict__ F2,
                                                   float* __restrict__ pacc1,
                                                   float* __restrict__ pz1) {
    __shared__ u16 whT[80 * 136];     // B-tile rows d=0..79 (64 data, 64=ones, 65..79 zero)
    const int t     = threadIdx.x;
    const int n0    = blockIdx.x * 64;
    const int h     = blockIdx.y;
    const int chunk = blockIdx.z;
    const int lane  = t & 63;
    const int l15   = lane & 15;
    const int q     = lane >> 4;
    const int wrow  = (t >> 6) * 16;
    const int ar    = wrow + l15;             // this lane's A row (n-local)
    #pragma unroll
    for (int i = 0; i < 9; ++i) {
        int flat = t + 256 * i;               // rows 64..79: 16*136 = 2176
        if (flat < 16 * 136) {
            int row = 64 + flat / 136;
            whT[row * 136 + (flat % 136)] = (row == 64) ? (u16)0x3F80 : (u16)0;
        }
    }
    f32x4 acc[5];
    #pragma unroll
    for (int df = 0; df < 5; ++df)
        #pragma unroll
        for (int r = 0; r < 4; ++r) acc[df][r] = 0.f;
    const float F1v = F1[h * N + n0 + ar];
    __syncthreads();

    const int mbeg = chunk * 2048;
    for (int m0 = mbeg; m0 < mbeg + 2048; m0 += 128) {
        // B-tile staging loads first (latency overlapped with mask-gen VALU)
        uint4 st[4];
        #pragma unroll
        for (int i = 0; i < 4; ++i) {
            int flat = t + 256 * i;
            int row = flat >> 4;
            int c8  = (flat & 15) * 8;
            st[i] = *(const uint4*)&Wh1T[((size_t)(h * 64 + row)) * 4096 + m0 + c8];
        }
        // A-frags in registers: row ar, cols m0 + 32ks + 8q + j
        const int*   ap = &adj1[(size_t)(n0 + ar) * N + m0 + q * 8];
        const float* fp = &F2[h * N + m0 + q * 8];
        bf16x8 aw[4];
        #pragma unroll
        for (int ks = 0; ks < 4; ++ks) {
            int4   a0 = *(const int4*)(ap + ks * 32);
            int4   a1v = *(const int4*)(ap + ks * 32 + 4);
            float4 g0 = *(const float4*)(fp + ks * 32);
            float4 g1 = *(const float4*)(fp + ks * 32 + 4);
            float t0 = F1v + g0.x, t1 = F1v + g0.y, t2 = F1v + g0.z, t3 = F1v + g0.w;
            float t4 = F1v + g1.x, t5 = F1v + g1.y, t6 = F1v + g1.z, t7 = F1v + g1.w;
            float w0 = a0.x  ? exp2f(fmaxf(t0, ALPHA * t0)) : 0.f;
            float w1 = a0.y  ? exp2f(fmaxf(t1, ALPHA * t1)) : 0.f;
            float w2 = a0.z  ? exp2f(fmaxf(t2, ALPHA * t2)) : 0.f;
            float w3 = a0.w  ? exp2f(fmaxf(t3, ALPHA * t3)) : 0.f;
            float w4 = a1v.x ? exp2f(fmaxf(t4, ALPHA * t4)) : 0.f;
            float w5 = a1v.y ? exp2f(fmaxf(t5, ALPHA * t5)) : 0.f;
            float w6 = a1v.z ? exp2f(fmaxf(t6, ALPHA * t6)) : 0.f;
            float w7 = a1v.w ? exp2f(fmaxf(t7, ALPHA * t7)) : 0.f;
            union { u32 u[4]; bf16x8 v; } pk;
            pk.u[0] = pkbf(w0, w1); pk.u[1] = pkbf(w2, w3);
            pk.u[2] = pkbf(w4, w5); pk.u[3] = pkbf(w6, w7);
            aw[ks] = pk.v;
        }
        __syncthreads();              // prev iter's B-frag reads complete
        #pragma unroll
        for (int i = 0; i < 4; ++i) {
            int flat = t + 256 * i;
            int row = flat >> 4;
            int c8  = (flat & 15) * 8;
            *(uint4*)&whT[row * 136 + c8] = st[i];
        }
        __syncthreads();
        #pragma unroll
        for (int ks = 0; ks < 4; ++ks) {
            int k0 = ks * 32 + q * 8;
            #pragma unroll
            for (int df = 0; df < 5; ++df) {
                bf16x8 b = *(const bf16x8*)&whT[(df * 16 + l15) * 136 + k0];
                acc[df] = __builtin_amdgcn_mfma_f32_16x16x32_bf16(aw[ks], b, acc[df], 0, 0, 0);
            }
        }
    }
    // raw partials; denominator from ones-col (d=64 -> acc[4], col 0 of frag)
    const size_t rowbase = (size_t)(chunk * 8 + h) * 4096 + n0;
    #pragma unroll
    for (int r = 0; r < 4; ++r) {
        int nl = wrow + q * 4 + r;
        float z = __shfl(acc[4][r], lane & 48);
        if (l15 == 0) pz1[rowbase + nl] = z;
        #pragma unroll
        for (int df = 0; df < 4; ++df)
            pacc1[(rowbase + nl) * 64 + df * 16 + l15] = acc[df][r];
    }
}

// ---------------- K3b: reduce 2 chunks, normalize, ELU -> h1 f32 ----------------
__global__ __launch_bounds__(256) void k3b_norm(const float* __restrict__ pacc1,
                                                const float* __restrict__ pz1,
                                                float* __restrict__ h1) {
    const int g = blockIdx.x * 256 + threadIdx.x;
    const int d = g & 63;
    const int h = (g >> 6) & 7;
    const int n = g >> 9;
    const size_t i0 = (size_t)h * 4096 + n;
    float s = pacc1[i0 * 64 + d] + pacc1[(i0 + 8 * 4096) * 64 + d];
    float z = pz1[i0] + pz1[i0 + 8 * 4096];
    float v = s / fmaxf(z, 1e-30f);
    h1[(size_t)n * 512 + h * 64 + d] = v > 0.f ? v : __expf(v) - 1.f;
}

// ---------------- K4: Wh2[n][c] = h1[n,:] @ Wo[:,c]  (f32) ----------------------
__global__ __launch_bounds__(256) void k4_gemm2(const float* __restrict__ h1,
                                                const float* __restrict__ Wo,
                                                float* __restrict__ Wh2) {
    const int t = threadIdx.x;
    const int c = t & 63;
    const int n = blockIdx.x * 4 + (t >> 6);
    if (c < NCLASS) {
        const float* hrow = &h1[(size_t)n * 512];
        float acc = 0.f;
        #pragma unroll 8
        for (int f = 0; f < 512; ++f)
            acc += hrow[f] * Wo[f * NCLASS + c];
        Wh2[(size_t)n * NCLASS + c] = acc;
    }
}

// ---------------- K4b: F1o/F2o (pre-scaled) + Wh2T bf16 [c][n] ------------------
__global__ __launch_bounds__(256) void k4b_fo(const float* __restrict__ Wh2,
                                              const float* __restrict__ ao,
                                              float* __restrict__ F1o,
                                              float* __restrict__ F2o,
                                              u16* __restrict__ Wh2T) {
    const int n = blockIdx.x * 256 + threadIdx.x;
    float s1 = 0.f, s2 = 0.f;
    #pragma unroll
    for (int c = 0; c < NCLASS; ++c) {
        float v = Wh2[(size_t)n * NCLASS + c];
        s1 += v * ao[c];
        s2 += v * ao[NCLASS + c];
        Wh2T[(size_t)c * 4096 + n] = f2b(v);
    }
    F1o[n] = s1 * LOG2E;
    F2o[n] = s2 * LOG2E;
}

// ---------------- K5a: layer-2 attention partials; A-frags in registers ---------
// grid (64 n-tiles, 16 m-chunks) x 256. LDS = B-tile only (17.4 KB).
__global__ __launch_bounds__(256, 5) void k5a_attn2(const int* __restrict__ adj0,
                                                    const u16* __restrict__ Wh2T,
                                                    const float* __restrict__ F1o,
                                                    const float* __restrict__ F2o,
                                                    float* __restrict__ pacc,
                                                    float* __restrict__ pz) {
    __shared__ u16 whT[64 * 136];     // rows 0..39 data, 48 = ones, rest zero
    const int t     = threadIdx.x;
    const int n0    = blockIdx.x * 64;
    const int chunk = blockIdx.y;
    const int mbase = chunk * 256;
    const int lane  = t & 63;
    const int l15   = lane & 15;
    const int q     = lane >> 4;
    const int wrow  = (t >> 6) * 16;
    const int ar    = wrow + l15;
    #pragma unroll
    for (int i = 0; i < 13; ++i) {
        int flat = t + 256 * i;               // rows 40..63: 24*136 = 3264
        if (flat < 24 * 136) {
            int row = 40 + flat / 136;
            whT[row * 136 + (flat % 136)] = (row == 48) ? (u16)0x3F80 : (u16)0;
        }
    }
    f32x4 acc[4];
    #pragma unroll
    for (int df = 0; df < 4; ++df)
        #pragma unroll
        for (int r = 0; r < 4; ++r) acc[df][r] = 0.f;
    const float F1v = F1o[n0 + ar];
    __syncthreads();

    for (int mt = 0; mt < 2; ++mt) {
        int m0 = mbase + mt * 128;
        uint4 st[3];
        #pragma unroll
        for (int i = 0; i < 3; ++i) {
            int flat = t + 256 * i;           // 40 rows x 16 chunks = 640
            if (flat < 640) {
                int row = flat >> 4;
                int c8  = (flat & 15) * 8;
                st[i] = *(const uint4*)&Wh2T[(size_t)row * 4096 + m0 + c8];
            }
        }
        const int*   ap = &adj0[(size_t)(n0 + ar) * N + m0 + q * 8];
        const float* fp = &F2o[m0 + q * 8];
        bf16x8 aw[4];
        #pragma unroll
        for (int ks = 0; ks < 4; ++ks) {
            int4   a0 = *(const int4*)(ap + ks * 32);
            int4   a1v = *(const int4*)(ap + ks * 32 + 4);
            float4 g0 = *(const float4*)(fp + ks * 32);
            float4 g1 = *(const float4*)(fp + ks * 32 + 4);
            float t0 = F1v + g0.x, t1 = F1v + g0.y, t2 = F1v + g0.z, t3 = F1v + g0.w;
            float t4 = F1v + g1.x, t5 = F1v + g1.y, t6 = F1v + g1.z, t7 = F1v + g1.w;
            float w0 = a0.x  ? exp2f(fmaxf(t0, ALPHA * t0)) : 0.f;
            float w1 = a0.y  ? exp2f(fmaxf(t1, ALPHA * t1)) : 0.f;
            float w2 = a0.z  ? exp2f(fmaxf(t2, ALPHA * t2)) : 0.f;
            float w3 = a0.w  ? exp2f(fmaxf(t3, ALPHA * t3)) : 0.f;
            float w4 = a1v.x ? exp2f(fmaxf(t4, ALPHA * t4)) : 0.f;
            float w5 = a1v.y ? exp2f(fmaxf(t5, ALPHA * t5)) : 0.f;
            float w6 = a1v.z ? exp2f(fmaxf(t6, ALPHA * t6)) : 0.f;
            float w7 = a1v.w ? exp2f(fmaxf(t7, ALPHA * t7)) : 0.f;
            union { u32 u[4]; bf16x8 v; } pk;
            pk.u[0] = pkbf(w0, w1); pk.u[1] = pkbf(w2, w3);
            pk.u[2] = pkbf(w4, w5); pk.u[3] = pkbf(w6, w7);
            aw[ks] = pk.v;
        }
        __syncthreads();
        #pragma unroll
        for (int i = 0; i < 3; ++i) {
            int flat = t + 256 * i;
            if (flat < 640) {
                int row = flat >> 4;
                int c8  = (flat & 15) * 8;
                *(uint4*)&whT[row * 136 + c8] = st[i];
            }
        }
        __syncthreads();
        #pragma unroll
        for (int ks = 0; ks < 4; ++ks) {
            int k0 = ks * 32 + q * 8;
            #pragma unroll
            for (int df = 0; df < 4; ++df) {
                bf16x8 b = *(const bf16x8*)&whT[(df * 16 + l15) * 136 + k0];
                acc[df] = __builtin_amdgcn_mfma_f32_16x16x32_bf16(aw[ks], b, acc[df], 0, 0, 0);
            }
        }
    }
    #pragma unroll
    for (int r = 0; r < 4; ++r) {
        int n = n0 + wrow + q * 4 + r;
        float z = __shfl(acc[3][r], lane & 48);
        if (l15 == 0) pz[(size_t)chunk * N + n] = z;
        #pragma unroll
        for (int df = 0; df < 3; ++df) {
            int c = df * 16 + l15;
            if (c < NCLASS)
                pacc[((size_t)chunk * N + n) * NCLASS + c] = acc[df][r];
        }
    }
}

// ---------------- K5b: reduce 16 chunks, ELU, log_softmax, f32 store ------------
__global__ __launch_bounds__(256) void k5b_final(const float* __restrict__ pacc,
                                                 const float* __restrict__ pz,
                                                 float* __restrict__ out) {
    const int t = threadIdx.x;
    const int lane = t & 63;
    const int n = blockIdx.x * 4 + (t >> 6);
    float s = 0.f, Z = 0.f;
    #pragma unroll
    for (int ch = 0; ch < 16; ++ch) {
        Z += pz[(size_t)ch * N + n];
        if (lane < NCLASS) s += pacc[((size_t)ch * N + n) * NCLASS + lane];
    }
    float v;
    if (lane < NCLASS) {
        v = s / fmaxf(Z, 1e-30f);
        v = v > 0.f ? v : __expf(v) - 1.f;
    } else {
        v = -INFINITY;
    }
    float mx = v;
    #pragma unroll
    for (int off = 32; off >= 1; off >>= 1) mx = fmaxf(mx, __shfl_xor(mx, off));
    float ex = (lane < NCLASS) ? __expf(v - mx) : 0.f;
    #pragma unroll
    for (int off = 32; off >= 1; off >>= 1) ex += __shfl_xor(ex, off);
    float lse = mx + __logf(ex);
    if (lane < NCLASS) out[(size_t)n * NCLASS + lane] = v - lse;
}

// ---------------------------------------------------------------------------------
extern "C" void kernel_launch(void* const* d_in, const int* in_sizes, int n_in,
                              void* d_out, int out_size, void* d_ws, size_t ws_size,
                              hipStream_t stream) {
    const float* x   = (const float*)d_in[0];
    const int*   adj = (const int*)d_in[1];
    const float* W1  = (const float*)d_in[2];
    const float* a1  = (const float*)d_in[3];
    const float* Wo  = (const float*)d_in[4];
    const float* ao  = (const float*)d_in[5];

    float* ws    = (float*)d_ws;
    float* h1    = ws;                        // 2,097,152
    float* F1    = h1 + 2097152;              // 32,768
    float* F2    = F1 + 32768;                // 32,768
    float* Wh2   = F2 + 32768;                // 163,840
    float* F1o   = Wh2 + 163840;              // 4,096
    float* F2o   = F1o + 4096;                // 4,096
    float* pz    = F2o + 4096;                // 65,536 (16*4096, k5a)
    float* pz1   = pz + 65536;                // 65,536 (2*8*4096, k3)
    u16*   Wh1T  = (u16*)(pz1 + 65536);       // 2,097,152 u16
    u16*   Wh2T  = Wh1T + 2097152;            // 163,840 u16
    float* R     = (float*)(Wh2T + 163840);   // 4,194,304 f32 shared region
    u16*   xb    = (u16*)R;                   // kcx -> k1m (dies before k3)
    u16*   W1b   = xb + 2097152;              // kcw -> k1m (dies before k3)
    float* pacc1 = R;                         // k3 -> k3b (2*8*4096*64)
    float* pacc  = R;                         // k5a -> k5b (16*4096*40)
    // total ~ 7.8M f32 ~= 31.2 MiB (ws is ~512 MB per harness poison traffic)

    const int* adj0 = adj;                    // layer-2 mask
    const int* adj1 = adj + (size_t)N * N;    // layer-1 mask

    hipLaunchKernelGGL(kcx,       dim3(1024),     dim3(256), 0, stream, x, xb);
    hipLaunchKernelGGL(kcw,       dim3(8, 8),     dim3(256), 0, stream, W1, W1b);
    hipLaunchKernelGGL(k1m_gemm1, dim3(64, 8),    dim3(256), 0, stream, xb, W1b, Wh1T);
    hipLaunchKernelGGL(k2_f12,    dim3(128),      dim3(256), 0, stream, Wh1T, a1, F1, F2);
    hipLaunchKernelGGL(k3_attn1,  dim3(64, 8, 2), dim3(256), 0, stream, adj1, Wh1T, F1, F2, pacc1, pz1);
    hipLaunchKernelGGL(k3b_norm,  dim3(8192),     dim3(256), 0, stream, pacc1, pz1, h1);
    hipLaunchKernelGGL(k4_gemm2,  dim3(1024),     dim3(256), 0, stream, h1, Wo, Wh2);
    hipLaunchKernelGGL(k4b_fo,    dim3(16),       dim3(256), 0, stream, Wh2, ao, F1o, F2o, Wh2T);
    hipLaunchKernelGGL(k5a_attn2, dim3(64, 16),   dim3(256), 0, stream, adj0, Wh2T, F1o, F2o, pacc, pz);
    hipLaunchKernelGGL(k5b_final, dim3(1024),     dim3(256), 0, stream, pacc, pz, (float*)d_out);
}

// Round 7
// 379.133 us; speedup vs baseline: 1.3440x; 1.3440x over previous
//
#include <hip/hip_runtime.h>
#include <hip/hip_bf16.h>

#define N      4096
#define NFEAT  512
#define NHID   64
#define NHEADS 8
#define NCLASS 40
#define ALPHA  0.2f
#define LOG2E  1.44269504f

typedef unsigned short u16;
typedef unsigned int   u32;
typedef __attribute__((ext_vector_type(8))) short bf16x8;
typedef __attribute__((ext_vector_type(4))) float f32x4;

// bf16 bits -> f32
__device__ __forceinline__ float b2f(u16 u) {
    return __uint_as_float(((u32)u) << 16);
}
// RNE-rounded value kept in HIGH 16 bits (no shift; perm extracts)
__device__ __forceinline__ u32 rnd_hi(float f) {
    u32 u = __float_as_uint(f);
    return u + 0x7FFFu + ((u >> 16) & 1u);
}
// pack two f32 -> two bf16 in one u32 (lo = first arg) via v_perm_b32
__device__ __forceinline__ u32 pkbf(float lo, float hi) {
    return __builtin_amdgcn_perm(rnd_hi(hi), rnd_hi(lo), 0x07060302);
}
// single f32 -> bf16 bits (RNE)
__device__ __forceinline__ u16 f2b(float f) {
    return (u16)(rnd_hi(f) >> 16);
}

// ---------------- KCX: x f32 -> xb bf16 (same layout) ---------------------------
__global__ __launch_bounds__(256) void kcx(const float* __restrict__ x,
                                           u16* __restrict__ xb) {
    const int g = blockIdx.x * 256 + threadIdx.x;       // 262144 threads x 8 elems
    const size_t base = (size_t)g * 8;
    float4 v0 = *(const float4*)&x[base];
    float4 v1 = *(const float4*)&x[base + 4];
    uint4 o;
    o.x = pkbf(v0.x, v0.y); o.y = pkbf(v0.z, v0.w);
    o.z = pkbf(v1.x, v1.y); o.w = pkbf(v1.z, v1.w);
    *(uint4*)&xb[base] = o;
}

// ---------------- KCW: W1 [h][f][d] f32 -> W1b bf16 [h][d][f] -------------------
__global__ __launch_bounds__(256) void kcw(const float* __restrict__ W1,
                                           u16* __restrict__ W1b) {
    __shared__ float ts[64 * 68];   // [f-local][d], pitch 68
    const int t  = threadIdx.x;
    const int f0 = blockIdx.x * 64;
    const int h  = blockIdx.y;
    #pragma unroll
    for (int i = 0; i < 4; ++i) {
        int flat = t + 256 * i;
        int row = flat >> 4;                    // f-local
        int c4  = (flat & 15) * 4;              // d
        *(float4*)&ts[row * 68 + c4] =
            *(const float4*)&W1[((size_t)h * 512 + f0 + row) * 64 + c4];
    }
    __syncthreads();
    const int d  = t >> 2;
    const int fs = (t & 3) * 16;
    u32 p[8];
    #pragma unroll
    for (int j = 0; j < 8; ++j)
        p[j] = pkbf(ts[(fs + 2 * j) * 68 + d], ts[(fs + 2 * j + 1) * 68 + d]);
    u32* dst = (u32*)&W1b[((size_t)(h * 64 + d)) * 512 + f0 + fs];
    *(uint4*)dst       = make_uint4(p[0], p[1], p[2], p[3]);
    *(uint4*)(dst + 4) = make_uint4(p[4], p[5], p[6], p[7]);
}

// ---------------- K1M: Wh1T[h][d][n] = bf16( sum_f xb[n,f] * W1b[h,d,f] ) -------
// grid (64 n-tiles, 8 heads) x 256; MFMA 16x16x32, writes transposed bf16 directly.
__global__ __launch_bounds__(256, 4) void k1m_gemm1(const u16* __restrict__ xb,
                                                    const u16* __restrict__ W1b,
                                                    u16* __restrict__ Wh1T) {
    __shared__ u16 xs[64 * 72];    // [n-local][f-chunk], pitch 72
    __shared__ u16 wvs[64 * 72];   // [d][f-chunk]
    const int t    = threadIdx.x;
    const int n0   = blockIdx.x * 64;
    const int h    = blockIdx.y;
    const int lane = t & 63;
    const int l15  = lane & 15;
    const int q    = lane >> 4;
    const int wrow = (t >> 6) * 16;
    f32x4 acc[4];
    #pragma unroll
    for (int df = 0; df < 4; ++df)
        #pragma unroll
        for (int r = 0; r < 4; ++r) acc[df][r] = 0.f;
    for (int f0 = 0; f0 < 512; f0 += 64) {
        uint4 sx[2], sw[2];
        #pragma unroll
        for (int i = 0; i < 2; ++i) {
            int flat = t + 256 * i;
            int row = flat >> 3;
            int c8  = (flat & 7) * 8;
            sx[i] = *(const uint4*)&xb[(size_t)(n0 + row) * 512 + f0 + c8];
            sw[i] = *(const uint4*)&W1b[((size_t)(h * 64 + row)) * 512 + f0 + c8];
        }
        __syncthreads();
        #pragma unroll
        for (int i = 0; i < 2; ++i) {
            int flat = t + 256 * i;
            int row = flat >> 3;
            int c8  = (flat & 7) * 8;
            *(uint4*)&xs[row * 72 + c8]  = sx[i];
            *(uint4*)&wvs[row * 72 + c8] = sw[i];
        }
        __syncthreads();
        #pragma unroll
        for (int ks = 0; ks < 2; ++ks) {
            int k0 = ks * 32 + q * 8;
            bf16x8 a = *(const bf16x8*)&xs[(wrow + l15) * 72 + k0];
            #pragma unroll
            for (int df = 0; df < 4; ++df) {
                bf16x8 b = *(const bf16x8*)&wvs[(df * 16 + l15) * 72 + k0];
                acc[df] = __builtin_amdgcn_mfma_f32_16x16x32_bf16(a, b, acc[df], 0, 0, 0);
            }
        }
    }
    // C row = q*4 + r (n-local), col = l15 (d-local); pack 4 consecutive n as bf16
    #pragma unroll
    for (int df = 0; df < 4; ++df) {
        uint2 o;
        o.x = pkbf(acc[df][0], acc[df][1]);
        o.y = pkbf(acc[df][2], acc[df][3]);
        *(uint2*)&Wh1T[((size_t)(h * 64 + df * 16 + l15)) * 4096 + n0 + wrow + q * 4] = o;
    }
}

// ---------------- K2: F1/F2 (pre-scaled by log2e) from Wh1T bf16 ----------------
__global__ __launch_bounds__(256) void k2_f12(const u16* __restrict__ Wh1T,
                                              const float* __restrict__ a1,
                                              float* __restrict__ F1,
                                              float* __restrict__ F2) {
    const int g = blockIdx.x * 256 + threadIdx.x;   // 32768 threads
    const int h = g >> 12;
    const int n = g & 4095;
    float s1 = 0.f, s2 = 0.f;
    #pragma unroll 8
    for (int d = 0; d < 64; ++d) {
        float v = b2f(Wh1T[((size_t)(h * 64 + d)) * 4096 + n]);
        s1 += v * a1[h * 128 + d];
        s2 += v * a1[h * 128 + 64 + d];
    }
    F1[h * 4096 + n] = s1 * LOG2E;
    F2[h * 4096 + n] = s2 * LOG2E;
}

// ---------------- K3: layer-1 attention partials via MFMA -----------------------
// R5 memory structure (LDS wbf tile, coalesced int4 adj, fused staging) + cheap math:
// w = exp2(max(t, 0.2t)), t = (F1+F2) already scaled by log2e; pkbf packing.
// grid (64 n-tiles, 8 heads, 2 m-chunks) x 256; 39.4 KB LDS -> 4 blocks/CU.
__global__ __launch_bounds__(256, 4) void k3_attn1(const int* __restrict__ adj1,
                                                   const u16* __restrict__ Wh1T,
                                                   const float* __restrict__ F1,
                                                   const float* __restrict__ F2,
                                                   float* __restrict__ pacc1,
                                                   float* __restrict__ pz1) {
    __shared__ u16  wbf[64 * 136];    // A-tile, pitch 136
    __shared__ u16  whT[80 * 136];    // B-tile rows d=0..79 (64 data, 64=ones, 65..79 zero)
    __shared__ float f1s[64];
    const int t     = threadIdx.x;
    const int n0    = blockIdx.x * 64;
    const int h     = blockIdx.y;
    const int chunk = blockIdx.z;
    const int lane  = t & 63;
    const int l15   = lane & 15;
    const int q     = lane >> 4;
    const int wrow  = (t >> 6) * 16;
    const int c4    = (t & 31) * 4;           // mask-gen: 4 consecutive cols
    const int rg    = t >> 5;                 // mask-gen: row group 0..7
    if (t < 64) f1s[t] = F1[h * N + n0 + t];
    #pragma unroll
    for (int i = 0; i < 9; ++i) {
        int flat = t + 256 * i;               // rows 64..79: 16*136 = 2176
        if (flat < 16 * 136) {
            int row = 64 + flat / 136;
            whT[row * 136 + (flat % 136)] = (row == 64) ? (u16)0x3F80 : (u16)0;
        }
    }
    f32x4 acc[5];
    #pragma unroll
    for (int df = 0; df < 5; ++df)
        #pragma unroll
        for (int r = 0; r < 4; ++r) acc[df][r] = 0.f;
    __syncthreads();

    const int mbeg = chunk * 2048;
    for (int m0 = mbeg; m0 < mbeg + 2048; m0 += 128) {
        // ---- stage: mask-gen (coalesced int4 adj) -> wbf, fused Wh1T copy -> whT ----
        float4 F2v = *(const float4*)&F2[h * N + m0 + c4];
        #pragma unroll
        for (int i = 0; i < 8; ++i) {
            int rr = rg + 8 * i;
            int4 a4 = *(const int4*)&adj1[(size_t)(n0 + rr) * N + m0 + c4];
            float f1v = f1s[rr];
            float t0 = f1v + F2v.x, t1 = f1v + F2v.y, t2 = f1v + F2v.z, t3 = f1v + F2v.w;
            float w0 = a4.x ? exp2f(fmaxf(t0, ALPHA * t0)) : 0.f;
            float w1 = a4.y ? exp2f(fmaxf(t1, ALPHA * t1)) : 0.f;
            float w2 = a4.z ? exp2f(fmaxf(t2, ALPHA * t2)) : 0.f;
            float w3 = a4.w ? exp2f(fmaxf(t3, ALPHA * t3)) : 0.f;
            uint2 pk;
            pk.x = pkbf(w0, w1);
            pk.y = pkbf(w2, w3);
            *(uint2*)&wbf[rr * 136 + c4] = pk;
        }
        #pragma unroll
        for (int i = 0; i < 4; ++i) {
            int flat = t + 256 * i;           // 64 rows x 16 chunks
            int row = flat >> 4;
            int c8  = (flat & 15) * 8;
            *(uint4*)&whT[row * 136 + c8] =
                *(const uint4*)&Wh1T[((size_t)(h * 64 + row)) * 4096 + m0 + c8];
        }
        __syncthreads();
        // ---- compute: 4 K-steps x 5 d-frags ----
        #pragma unroll
        for (int ks = 0; ks < 4; ++ks) {
            int k0 = ks * 32 + q * 8;
            bf16x8 a = *(const bf16x8*)&wbf[(wrow + l15) * 136 + k0];
            #pragma unroll
            for (int df = 0; df < 5; ++df) {
                bf16x8 b = *(const bf16x8*)&whT[(df * 16 + l15) * 136 + k0];
                acc[df] = __builtin_amdgcn_mfma_f32_16x16x32_bf16(a, b, acc[df], 0, 0, 0);
            }
        }
        __syncthreads();
    }
    // raw partials; denominator from ones-col (d=64 -> acc[4], col 0 of frag)
    const size_t rowbase = (size_t)(chunk * 8 + h) * 4096 + n0;
    #pragma unroll
    for (int r = 0; r < 4; ++r) {
        int nl = wrow + q * 4 + r;
        float z = __shfl(acc[4][r], lane & 48);
        if (l15 == 0) pz1[rowbase + nl] = z;
        #pragma unroll
        for (int df = 0; df < 4; ++df)
            pacc1[(rowbase + nl) * 64 + df * 16 + l15] = acc[df][r];
    }
}

// ---------------- K3b: reduce 2 chunks, normalize, ELU -> h1 f32 ----------------
__global__ __launch_bounds__(256) void k3b_norm(const float* __restrict__ pacc1,
                                                const float* __restrict__ pz1,
                                                float* __restrict__ h1) {
    const int g = blockIdx.x * 256 + threadIdx.x;
    const int d = g & 63;
    const int h = (g >> 6) & 7;
    const int n = g >> 9;
    const size_t i0 = (size_t)h * 4096 + n;
    float s = pacc1[i0 * 64 + d] + pacc1[(i0 + 8 * 4096) * 64 + d];
    float z = pz1[i0] + pz1[i0 + 8 * 4096];
    float v = s / fmaxf(z, 1e-30f);
    h1[(size_t)n * 512 + h * 64 + d] = v > 0.f ? v : __expf(v) - 1.f;
}

// ---------------- K4: Wh2[n][c] = h1[n,:] @ Wo[:,c]  (f32) ----------------------
__global__ __launch_bounds__(256) void k4_gemm2(const float* __restrict__ h1,
                                                const float* __restrict__ Wo,
                                                float* __restrict__ Wh2) {
    const int t = threadIdx.x;
    const int c = t & 63;
    const int n = blockIdx.x * 4 + (t >> 6);
    if (c < NCLASS) {
        const float* hrow = &h1[(size_t)n * 512];
        float acc = 0.f;
        #pragma unroll 8
        for (int f = 0; f < 512; ++f)
            acc += hrow[f] * Wo[f * NCLASS + c];
        Wh2[(size_t)n * NCLASS + c] = acc;
    }
}

// ---------------- K4b: F1o/F2o (pre-scaled) + Wh2T bf16 [c][n] ------------------
__global__ __launch_bounds__(256) void k4b_fo(const float* __restrict__ Wh2,
                                              const float* __restrict__ ao,
                                              float* __restrict__ F1o,
                                              float* __restrict__ F2o,
                                              u16* __restrict__ Wh2T) {
    const int n = blockIdx.x * 256 + threadIdx.x;
    float s1 = 0.f, s2 = 0.f;
    #pragma unroll
    for (int c = 0; c < NCLASS; ++c) {
        float v = Wh2[(size_t)n * NCLASS + c];
        s1 += v * ao[c];
        s2 += v * ao[NCLASS + c];
        Wh2T[(size_t)c * 4096 + n] = f2b(v);
    }
    F1o[n] = s1 * LOG2E;
    F2o[n] = s2 * LOG2E;
}

// ---------------- K5a: layer-2 attention partials via MFMA ----------------------
// R5 structure + cheap math. grid (64 n-tiles, 16 m-chunks) x 256; 4+ blocks/CU.
__global__ __launch_bounds__(256, 4) void k5a_attn2(const int* __restrict__ adj0,
                                                    const u16* __restrict__ Wh2T,
                                                    const float* __restrict__ F1o,
                                                    const float* __restrict__ F2o,
                                                    float* __restrict__ pacc,
                                                    float* __restrict__ pz) {
    __shared__ u16  wbf[64 * 136];
    __shared__ u16  whT[64 * 136];    // rows 0..39 data, 48 ones, others zero
    __shared__ float f1s[64];
    const int t     = threadIdx.x;
    const int n0    = blockIdx.x * 64;
    const int chunk = blockIdx.y;
    const int mbase = chunk * 256;
    const int lane  = t & 63;
    const int l15   = lane & 15;
    const int q     = lane >> 4;
    const int wrow  = (t >> 6) * 16;
    const int c4    = (t & 31) * 4;
    const int rg    = t >> 5;
    if (t < 64) f1s[t] = F1o[n0 + t];
    #pragma unroll
    for (int i = 0; i < 13; ++i) {
        int flat = t + 256 * i;               // rows 40..63: 24*136 = 3264
        if (flat < 24 * 136) {
            int row = 40 + flat / 136;
            whT[row * 136 + (flat % 136)] = (row == 48) ? (u16)0x3F80 : (u16)0;
        }
    }
    f32x4 acc[4];
    #pragma unroll
    for (int df = 0; df < 4; ++df)
        #pragma unroll
        for (int r = 0; r < 4; ++r) acc[df][r] = 0.f;
    __syncthreads();

    for (int mt = 0; mt < 2; ++mt) {
        int m0 = mbase + mt * 128;
        float4 F2v = *(const float4*)&F2o[m0 + c4];
        #pragma unroll
        for (int i = 0; i < 8; ++i) {
            int rr = rg + 8 * i;
            int4 a4 = *(const int4*)&adj0[(size_t)(n0 + rr) * N + m0 + c4];
            float f1v = f1s[rr];
            float t0 = f1v + F2v.x, t1 = f1v + F2v.y, t2 = f1v + F2v.z, t3 = f1v + F2v.w;
            float w0 = a4.x ? exp2f(fmaxf(t0, ALPHA * t0)) : 0.f;
            float w1 = a4.y ? exp2f(fmaxf(t1, ALPHA * t1)) : 0.f;
            float w2 = a4.z ? exp2f(fmaxf(t2, ALPHA * t2)) : 0.f;
            float w3 = a4.w ? exp2f(fmaxf(t3, ALPHA * t3)) : 0.f;
            uint2 pk;
            pk.x = pkbf(w0, w1);
            pk.y = pkbf(w2, w3);
            *(uint2*)&wbf[rr * 136 + c4] = pk;
        }
        #pragma unroll
        for (int i = 0; i < 3; ++i) {
            int flat = t + 256 * i;           // 40 rows x 16 chunks = 640
            if (flat < 640) {
                int row = flat >> 4;
                int c8  = (flat & 15) * 8;
                *(uint4*)&whT[row * 136 + c8] =
                    *(const uint4*)&Wh2T[(size_t)row * 4096 + m0 + c8];
            }
        }
        __syncthreads();
        #pragma unroll
        for (int ks = 0; ks < 4; ++ks) {
            int k0 = ks * 32 + q * 8;
            bf16x8 a = *(const bf16x8*)&wbf[(wrow + l15) * 136 + k0];
            #pragma unroll
            for (int df = 0; df < 4; ++df) {
                bf16x8 b = *(const bf16x8*)&whT[(df * 16 + l15) * 136 + k0];
                acc[df] = __builtin_amdgcn_mfma_f32_16x16x32_bf16(a, b, acc[df], 0, 0, 0);
            }
        }
        __syncthreads();
    }
    #pragma unroll
    for (int r = 0; r < 4; ++r) {
        int n = n0 + wrow + q * 4 + r;
        float z = __shfl(acc[3][r], lane & 48);
        if (l15 == 0) pz[(size_t)chunk * N + n] = z;
        #pragma unroll
        for (int df = 0; df < 3; ++df) {
            int c = df * 16 + l15;
            if (c < NCLASS)
                pacc[((size_t)chunk * N + n) * NCLASS + c] = acc[df][r];
        }
    }
}

// ---------------- K5b: reduce 16 chunks, ELU, log_softmax, f32 store ------------
__global__ __launch_bounds__(256) void k5b_final(const float* __restrict__ pacc,
                                                 const float* __restrict__ pz,
                                                 float* __restrict__ out) {
    const int t = threadIdx.x;
    const int lane = t & 63;
    const int n = blockIdx.x * 4 + (t >> 6);
    float s = 0.f, Z = 0.f;
    #pragma unroll
    for (int ch = 0; ch < 16; ++ch) {
        Z += pz[(size_t)ch * N + n];
        if (lane < NCLASS) s += pacc[(size_t)(ch * N + n) * NCLASS + lane];
    }
    float v;
    if (lane < NCLASS) {
        v = s / fmaxf(Z, 1e-30f);
        v = v > 0.f ? v : __expf(v) - 1.f;
    } else {
        v = -INFINITY;
    }
    float mx = v;
    #pragma unroll
    for (int off = 32; off >= 1; off >>= 1) mx = fmaxf(mx, __shfl_xor(mx, off));
    float ex = (lane < NCLASS) ? __expf(v - mx) : 0.f;
    #pragma unroll
    for (int off = 32; off >= 1; off >>= 1) ex += __shfl_xor(ex, off);
    float lse = mx + __logf(ex);
    if (lane < NCLASS) out[(size_t)n * NCLASS + lane] = v - lse;
}

// ---------------------------------------------------------------------------------
extern "C" void kernel_launch(void* const* d_in, const int* in_sizes, int n_in,
                              void* d_out, int out_size, void* d_ws, size_t ws_size,
                              hipStream_t stream) {
    const float* x   = (const float*)d_in[0];
    const int*   adj = (const int*)d_in[1];
    const float* W1  = (const float*)d_in[2];
    const float* a1  = (const float*)d_in[3];
    const float* Wo  = (const float*)d_in[4];
    const float* ao  = (const float*)d_in[5];

    float* ws    = (float*)d_ws;
    float* h1    = ws;                        // 2,097,152
    float* F1    = h1 + 2097152;              // 32,768
    float* F2    = F1 + 32768;                // 32,768
    float* Wh2   = F2 + 32768;                // 163,840
    float* F1o   = Wh2 + 163840;              // 4,096
    float* F2o   = F1o + 4096;                // 4,096
    float* pz    = F2o + 4096;                // 65,536 (16*4096, k5a)
    float* pz1   = pz + 65536;                // 65,536 (2*8*4096, k3)
    u16*   Wh1T  = (u16*)(pz1 + 65536);       // 2,097,152 u16
    u16*   Wh2T  = Wh1T + 2097152;            // 163,840 u16
    float* R     = (float*)(Wh2T + 163840);   // 4,194,304 f32 shared region
    u16*   xb    = (u16*)R;                   // kcx -> k1m (dies before k3)
    u16*   W1b   = xb + 2097152;              // kcw -> k1m (dies before k3)
    float* pacc1 = R;                         // k3 -> k3b (2*8*4096*64)
    float* pacc  = R;                         // k5a -> k5b (16*4096*40)

    const int* adj0 = adj;                    // layer-2 mask
    const int* adj1 = adj + (size_t)N * N;    // layer-1 mask

    hipLaunchKernelGGL(kcx,       dim3(1024),     dim3(256), 0, stream, x, xb);
    hipLaunchKernelGGL(kcw,       dim3(8, 8),     dim3(256), 0, stream, W1, W1b);
    hipLaunchKernelGGL(k1m_gemm1, dim3(64, 8),    dim3(256), 0, stream, xb, W1b, Wh1T);
    hipLaunchKernelGGL(k2_f12,    dim3(128),      dim3(256), 0, stream, Wh1T, a1, F1, F2);
    hipLaunchKernelGGL(k3_attn1,  dim3(64, 8, 2), dim3(256), 0, stream, adj1, Wh1T, F1, F2, pacc1, pz1);
    hipLaunchKernelGGL(k3b_norm,  dim3(8192),     dim3(256), 0, stream, pacc1, pz1, h1);
    hipLaunchKernelGGL(k4_gemm2,  dim3(1024),     dim3(256), 0, stream, h1, Wo, Wh2);
    hipLaunchKernelGGL(k4b_fo,    dim3(16),       dim3(256), 0, stream, Wh2, ao, F1o, F2o, Wh2T);
    hipLaunchKernelGGL(k5a_attn2, dim3(64, 16),   dim3(256), 0, stream, adj0, Wh2T, F1o, F2o, pacc, pz);
    hipLaunchKernelGGL(k5b_final, dim3(1024),     dim3(256), 0, stream, pacc, pz, (float*)d_out);
}

// Round 8
// 347.738 us; speedup vs baseline: 1.4653x; 1.0903x over previous
//
#include <hip/hip_runtime.h>
#include <hip/hip_bf16.h>

#define N      4096
#define NFEAT  512
#define NHID   64
#define NHEADS 8
#define NCLASS 40
#define ALPHA  0.2f
#define LOG2E  1.44269504f

typedef unsigned short u16;
typedef unsigned int   u32;
typedef __attribute__((ext_vector_type(8))) short bf16x8;
typedef __attribute__((ext_vector_type(4))) float f32x4;

// bf16 bits -> f32
__device__ __forceinline__ float b2f(u16 u) {
    return __uint_as_float(((u32)u) << 16);
}
// RNE-rounded value kept in HIGH 16 bits
__device__ __forceinline__ u32 rnd_hi(float f) {
    u32 u = __float_as_uint(f);
    return u + 0x7FFFu + ((u >> 16) & 1u);
}
// pack two f32 -> two bf16 (lo in low 16) via HW v_cvt_pk_bf16_f32 (gfx950)
__device__ __forceinline__ u32 pk2(float lo, float hi) {
    __hip_bfloat162 h = __float22bfloat162_rn(make_float2(lo, hi));
    return *(u32*)&h;
}
// single f32 -> bf16 bits (RNE)
__device__ __forceinline__ u16 f2b(float f) {
    return (u16)(rnd_hi(f) >> 16);
}
// masked exp2 of leaky-relu in log2 domain: raw v_exp_f32, no OCML guards
__device__ __forceinline__ float mexp(int m, float t) {
    return m ? __builtin_amdgcn_exp2f(fmaxf(t, ALPHA * t)) : 0.f;
}

// ---------------- KCX: x f32 -> xb bf16 (same layout) ---------------------------
__global__ __launch_bounds__(256) void kcx(const float* __restrict__ x,
                                           u16* __restrict__ xb) {
    const int g = blockIdx.x * 256 + threadIdx.x;       // 262144 threads x 8 elems
    const size_t base = (size_t)g * 8;
    float4 v0 = *(const float4*)&x[base];
    float4 v1 = *(const float4*)&x[base + 4];
    uint4 o;
    o.x = pk2(v0.x, v0.y); o.y = pk2(v0.z, v0.w);
    o.z = pk2(v1.x, v1.y); o.w = pk2(v1.z, v1.w);
    *(uint4*)&xb[base] = o;
}

// ---------------- KCW: W1 [h][f][d] f32 -> W1b bf16 [h][d][f] -------------------
__global__ __launch_bounds__(256) void kcw(const float* __restrict__ W1,
                                           u16* __restrict__ W1b) {
    __shared__ float ts[64 * 68];   // [f-local][d], pitch 68
    const int t  = threadIdx.x;
    const int f0 = blockIdx.x * 64;
    const int h  = blockIdx.y;
    #pragma unroll
    for (int i = 0; i < 4; ++i) {
        int flat = t + 256 * i;
        int row = flat >> 4;                    // f-local
        int c4  = (flat & 15) * 4;              // d
        *(float4*)&ts[row * 68 + c4] =
            *(const float4*)&W1[((size_t)h * 512 + f0 + row) * 64 + c4];
    }
    __syncthreads();
    const int d  = t >> 2;
    const int fs = (t & 3) * 16;
    u32 p[8];
    #pragma unroll
    for (int j = 0; j < 8; ++j)
        p[j] = pk2(ts[(fs + 2 * j) * 68 + d], ts[(fs + 2 * j + 1) * 68 + d]);
    u32* dst = (u32*)&W1b[((size_t)(h * 64 + d)) * 512 + f0 + fs];
    *(uint4*)dst       = make_uint4(p[0], p[1], p[2], p[3]);
    *(uint4*)(dst + 4) = make_uint4(p[4], p[5], p[6], p[7]);
}

// ---------------- K1M: Wh1T[h][d][n] = bf16( sum_f xb[n,f] * W1b[h,d,f] ) -------
__global__ __launch_bounds__(256, 4) void k1m_gemm1(const u16* __restrict__ xb,
                                                    const u16* __restrict__ W1b,
                                                    u16* __restrict__ Wh1T) {
    __shared__ u16 xs[64 * 72];    // [n-local][f-chunk], pitch 72
    __shared__ u16 wvs[64 * 72];   // [d][f-chunk]
    const int t    = threadIdx.x;
    const int n0   = blockIdx.x * 64;
    const int h    = blockIdx.y;
    const int lane = t & 63;
    const int l15  = lane & 15;
    const int q    = lane >> 4;
    const int wrow = (t >> 6) * 16;
    f32x4 acc[4];
    #pragma unroll
    for (int df = 0; df < 4; ++df)
        #pragma unroll
        for (int r = 0; r < 4; ++r) acc[df][r] = 0.f;
    for (int f0 = 0; f0 < 512; f0 += 64) {
        uint4 sx[2], sw[2];
        #pragma unroll
        for (int i = 0; i < 2; ++i) {
            int flat = t + 256 * i;
            int row = flat >> 3;
            int c8  = (flat & 7) * 8;
            sx[i] = *(const uint4*)&xb[(size_t)(n0 + row) * 512 + f0 + c8];
            sw[i] = *(const uint4*)&W1b[((size_t)(h * 64 + row)) * 512 + f0 + c8];
        }
        __syncthreads();
        #pragma unroll
        for (int i = 0; i < 2; ++i) {
            int flat = t + 256 * i;
            int row = flat >> 3;
            int c8  = (flat & 7) * 8;
            *(uint4*)&xs[row * 72 + c8]  = sx[i];
            *(uint4*)&wvs[row * 72 + c8] = sw[i];
        }
        __syncthreads();
        #pragma unroll
        for (int ks = 0; ks < 2; ++ks) {
            int k0 = ks * 32 + q * 8;
            bf16x8 a = *(const bf16x8*)&xs[(wrow + l15) * 72 + k0];
            #pragma unroll
            for (int df = 0; df < 4; ++df) {
                bf16x8 b = *(const bf16x8*)&wvs[(df * 16 + l15) * 72 + k0];
                acc[df] = __builtin_amdgcn_mfma_f32_16x16x32_bf16(a, b, acc[df], 0, 0, 0);
            }
        }
    }
    #pragma unroll
    for (int df = 0; df < 4; ++df) {
        uint2 o;
        o.x = pk2(acc[df][0], acc[df][1]);
        o.y = pk2(acc[df][2], acc[df][3]);
        *(uint2*)&Wh1T[((size_t)(h * 64 + df * 16 + l15)) * 4096 + n0 + wrow + q * 4] = o;
    }
}

// ---------------- K2: F1/F2 (pre-scaled by log2e) from Wh1T bf16 ----------------
__global__ __launch_bounds__(256) void k2_f12(const u16* __restrict__ Wh1T,
                                              const float* __restrict__ a1,
                                              float* __restrict__ F1,
                                              float* __restrict__ F2) {
    const int g = blockIdx.x * 256 + threadIdx.x;   // 32768 threads
    const int h = g >> 12;
    const int n = g & 4095;
    float s1 = 0.f, s2 = 0.f;
    #pragma unroll 8
    for (int d = 0; d < 64; ++d) {
        float v = b2f(Wh1T[((size_t)(h * 64 + d)) * 4096 + n]);
        s1 += v * a1[h * 128 + d];
        s2 += v * a1[h * 128 + 64 + d];
    }
    F1[h * 4096 + n] = s1 * LOG2E;
    F2[h * 4096 + n] = s2 * LOG2E;
}

// ---------------- K3: layer-1 attention partials via MFMA -----------------------
// R5 memory structure + HW-exp/HW-pack mask-gen + register adj prefetch.
// grid (64 n-tiles, 8 heads, 2 m-chunks) x 256; 39.4 KB LDS -> 4 blocks/CU.
__global__ __launch_bounds__(256, 4) void k3_attn1(const int* __restrict__ adj1,
                                                   const u16* __restrict__ Wh1T,
                                                   const float* __restrict__ F1,
                                                   const float* __restrict__ F2,
                                                   float* __restrict__ pacc1,
                                                   float* __restrict__ pz1) {
    __shared__ u16  wbf[64 * 136];    // A-tile, pitch 136
    __shared__ u16  whT[80 * 136];    // B-tile rows d=0..79 (64 data, 64=ones, 65..79 zero)
    __shared__ float f1s[64];
    const int t     = threadIdx.x;
    const int n0    = blockIdx.x * 64;
    const int h     = blockIdx.y;
    const int chunk = blockIdx.z;
    const int lane  = t & 63;
    const int l15   = lane & 15;
    const int q     = lane >> 4;
    const int wrow  = (t >> 6) * 16;
    const int c4    = (t & 31) * 4;           // mask-gen: 4 consecutive cols
    const int rg    = t >> 5;                 // mask-gen: row group 0..7
    if (t < 64) f1s[t] = F1[h * N + n0 + t];
    #pragma unroll
    for (int i = 0; i < 9; ++i) {
        int flat = t + 256 * i;               // rows 64..79: 16*136 = 2176
        if (flat < 16 * 136) {
            int row = 64 + flat / 136;
            whT[row * 136 + (flat % 136)] = (row == 64) ? (u16)0x3F80 : (u16)0;
        }
    }
    f32x4 acc[5];
    #pragma unroll
    for (int df = 0; df < 5; ++df)
        #pragma unroll
        for (int r = 0; r < 4; ++r) acc[df][r] = 0.f;

    const int mbeg = chunk * 2048;
    // preload iter-0 adj tile into registers (8 x int4 = 32 VGPRs)
    int4 aprev[8];
    #pragma unroll
    for (int i = 0; i < 8; ++i)
        aprev[i] = *(const int4*)&adj1[(size_t)(n0 + rg + 8 * i) * N + mbeg + c4];
    __syncthreads();

    for (int m0 = mbeg; m0 < mbeg + 2048; m0 += 128) {
        // ---- mask-gen from prefetched adj regs -> wbf (HW exp2 + HW bf16 pack) ----
        float4 F2v = *(const float4*)&F2[h * N + m0 + c4];
        #pragma unroll
        for (int i = 0; i < 8; ++i) {
            int rr = rg + 8 * i;
            int4 a4 = aprev[i];
            float f1v = f1s[rr];
            float w0 = mexp(a4.x, f1v + F2v.x);
            float w1 = mexp(a4.y, f1v + F2v.y);
            float w2 = mexp(a4.z, f1v + F2v.z);
            float w3 = mexp(a4.w, f1v + F2v.w);
            uint2 pk;
            pk.x = pk2(w0, w1);
            pk.y = pk2(w2, w3);
            *(uint2*)&wbf[rr * 136 + c4] = pk;
        }
        // ---- prefetch next iter's adj (wraps to mbeg on last iter; harmless) ----
        int mn = (m0 + 128 < mbeg + 2048) ? m0 + 128 : mbeg;
        #pragma unroll
        for (int i = 0; i < 8; ++i)
            aprev[i] = *(const int4*)&adj1[(size_t)(n0 + rg + 8 * i) * N + mn + c4];
        // ---- stage B-tile ----
        #pragma unroll
        for (int i = 0; i < 4; ++i) {
            int flat = t + 256 * i;           // 64 rows x 16 chunks
            int row = flat >> 4;
            int c8  = (flat & 15) * 8;
            *(uint4*)&whT[row * 136 + c8] =
                *(const uint4*)&Wh1T[((size_t)(h * 64 + row)) * 4096 + m0 + c8];
        }
        __syncthreads();
        // ---- compute: 4 K-steps x 5 d-frags ----
        #pragma unroll
        for (int ks = 0; ks < 4; ++ks) {
            int k0 = ks * 32 + q * 8;
            bf16x8 a = *(const bf16x8*)&wbf[(wrow + l15) * 136 + k0];
            #pragma unroll
            for (int df = 0; df < 5; ++df) {
                bf16x8 b = *(const bf16x8*)&whT[(df * 16 + l15) * 136 + k0];
                acc[df] = __builtin_amdgcn_mfma_f32_16x16x32_bf16(a, b, acc[df], 0, 0, 0);
            }
        }
        __syncthreads();
    }
    // raw partials; denominator from ones-col (d=64 -> acc[4])
    const size_t rowbase = (size_t)(chunk * 8 + h) * 4096 + n0;
    #pragma unroll
    for (int r = 0; r < 4; ++r) {
        int nl = wrow + q * 4 + r;
        float z = __shfl(acc[4][r], lane & 48);
        if (l15 == 0) pz1[rowbase + nl] = z;
        #pragma unroll
        for (int df = 0; df < 4; ++df)
            pacc1[(rowbase + nl) * 64 + df * 16 + l15] = acc[df][r];
    }
}

// ---------------- K3b: reduce 2 chunks, normalize, ELU -> h1 f32 ----------------
__global__ __launch_bounds__(256) void k3b_norm(const float* __restrict__ pacc1,
                                                const float* __restrict__ pz1,
                                                float* __restrict__ h1) {
    const int g = blockIdx.x * 256 + threadIdx.x;
    const int d = g & 63;
    const int h = (g >> 6) & 7;
    const int n = g >> 9;
    const size_t i0 = (size_t)h * 4096 + n;
    float s = pacc1[i0 * 64 + d] + pacc1[(i0 + 8 * 4096) * 64 + d];
    float z = pz1[i0] + pz1[i0 + 8 * 4096];
    float v = s / fmaxf(z, 1e-30f);
    h1[(size_t)n * 512 + h * 64 + d] = v > 0.f ? v : __expf(v) - 1.f;
}

// ---------------- K4: Wh2[n][c] = h1[n,:] @ Wo[:,c]  (f32) ----------------------
__global__ __launch_bounds__(256) void k4_gemm2(const float* __restrict__ h1,
                                                const float* __restrict__ Wo,
                                                float* __restrict__ Wh2) {
    const int t = threadIdx.x;
    const int c = t & 63;
    const int n = blockIdx.x * 4 + (t >> 6);
    if (c < NCLASS) {
        const float* hrow = &h1[(size_t)n * 512];
        float acc = 0.f;
        #pragma unroll 8
        for (int f = 0; f < 512; ++f)
            acc += hrow[f] * Wo[f * NCLASS + c];
        Wh2[(size_t)n * NCLASS + c] = acc;
    }
}

// ---------------- K4b: F1o/F2o (pre-scaled) + Wh2T bf16 [c][n] ------------------
__global__ __launch_bounds__(256) void k4b_fo(const float* __restrict__ Wh2,
                                              const float* __restrict__ ao,
                                              float* __restrict__ F1o,
                                              float* __restrict__ F2o,
                                              u16* __restrict__ Wh2T) {
    const int n = blockIdx.x * 256 + threadIdx.x;
    float s1 = 0.f, s2 = 0.f;
    #pragma unroll
    for (int c = 0; c < NCLASS; ++c) {
        float v = Wh2[(size_t)n * NCLASS + c];
        s1 += v * ao[c];
        s2 += v * ao[NCLASS + c];
        Wh2T[(size_t)c * 4096 + n] = f2b(v);
    }
    F1o[n] = s1 * LOG2E;
    F2o[n] = s2 * LOG2E;
}

// ---------------- K5a: layer-2 attention partials via MFMA ----------------------
// grid (64 n-tiles, 16 m-chunks) x 256; same opts as k3.
__global__ __launch_bounds__(256, 4) void k5a_attn2(const int* __restrict__ adj0,
                                                    const u16* __restrict__ Wh2T,
                                                    const float* __restrict__ F1o,
                                                    const float* __restrict__ F2o,
                                                    float* __restrict__ pacc,
                                                    float* __restrict__ pz) {
    __shared__ u16  wbf[64 * 136];
    __shared__ u16  whT[64 * 136];    // rows 0..39 data, 48 ones, others zero
    __shared__ float f1s[64];
    const int t     = threadIdx.x;
    const int n0    = blockIdx.x * 64;
    const int chunk = blockIdx.y;
    const int mbase = chunk * 256;
    const int lane  = t & 63;
    const int l15   = lane & 15;
    const int q     = lane >> 4;
    const int wrow  = (t >> 6) * 16;
    const int c4    = (t & 31) * 4;
    const int rg    = t >> 5;
    if (t < 64) f1s[t] = F1o[n0 + t];
    #pragma unroll
    for (int i = 0; i < 13; ++i) {
        int flat = t + 256 * i;               // rows 40..63: 24*136 = 3264
        if (flat < 24 * 136) {
            int row = 40 + flat / 136;
            whT[row * 136 + (flat % 136)] = (row == 48) ? (u16)0x3F80 : (u16)0;
        }
    }
    f32x4 acc[4];
    #pragma unroll
    for (int df = 0; df < 4; ++df)
        #pragma unroll
        for (int r = 0; r < 4; ++r) acc[df][r] = 0.f;
    int4 aprev[8];
    #pragma unroll
    for (int i = 0; i < 8; ++i)
        aprev[i] = *(const int4*)&adj0[(size_t)(n0 + rg + 8 * i) * N + mbase + c4];
    __syncthreads();

    for (int mt = 0; mt < 2; ++mt) {
        int m0 = mbase + mt * 128;
        float4 F2v = *(const float4*)&F2o[m0 + c4];
        #pragma unroll
        for (int i = 0; i < 8; ++i) {
            int rr = rg + 8 * i;
            int4 a4 = aprev[i];
            float f1v = f1s[rr];
            float w0 = mexp(a4.x, f1v + F2v.x);
            float w1 = mexp(a4.y, f1v + F2v.y);
            float w2 = mexp(a4.z, f1v + F2v.z);
            float w3 = mexp(a4.w, f1v + F2v.w);
            uint2 pk;
            pk.x = pk2(w0, w1);
            pk.y = pk2(w2, w3);
            *(uint2*)&wbf[rr * 136 + c4] = pk;
        }
        int mn = mbase + ((mt + 1) & 1) * 128;
        #pragma unroll
        for (int i = 0; i < 8; ++i)
            aprev[i] = *(const int4*)&adj0[(size_t)(n0 + rg + 8 * i) * N + mn + c4];
        #pragma unroll
        for (int i = 0; i < 3; ++i) {
            int flat = t + 256 * i;           // 40 rows x 16 chunks = 640
            if (flat < 640) {
                int row = flat >> 4;
                int c8  = (flat & 15) * 8;
                *(uint4*)&whT[row * 136 + c8] =
                    *(const uint4*)&Wh2T[(size_t)row * 4096 + m0 + c8];
            }
        }
        __syncthreads();
        #pragma unroll
        for (int ks = 0; ks < 4; ++ks) {
            int k0 = ks * 32 + q * 8;
            bf16x8 a = *(const bf16x8*)&wbf[(wrow + l15) * 136 + k0];
            #pragma unroll
            for (int df = 0; df < 4; ++df) {
                bf16x8 b = *(const bf16x8*)&whT[(df * 16 + l15) * 136 + k0];
                acc[df] = __builtin_amdgcn_mfma_f32_16x16x32_bf16(a, b, acc[df], 0, 0, 0);
            }
        }
        __syncthreads();
    }
    #pragma unroll
    for (int r = 0; r < 4; ++r) {
        int n = n0 + wrow + q * 4 + r;
        float z = __shfl(acc[3][r], lane & 48);
        if (l15 == 0) pz[(size_t)chunk * N + n] = z;
        #pragma unroll
        for (int df = 0; df < 3; ++df) {
            int c = df * 16 + l15;
            if (c < NCLASS)
                pacc[((size_t)chunk * N + n) * NCLASS + c] = acc[df][r];
        }
    }
}

// ---------------- K5b: reduce 16 chunks, ELU, log_softmax, f32 store ------------
__global__ __launch_bounds__(256) void k5b_final(const float* __restrict__ pacc,
                                                 const float* __restrict__ pz,
                                                 float* __restrict__ out) {
    const int t = threadIdx.x;
    const int lane = t & 63;
    const int n = blockIdx.x * 4 + (t >> 6);
    float s = 0.f, Z = 0.f;
    #pragma unroll
    for (int ch = 0; ch < 16; ++ch) {
        Z += pz[(size_t)ch * N + n];
        if (lane < NCLASS) s += pacc[(size_t)(ch * N + n) * NCLASS + lane];
    }
    float v;
    if (lane < NCLASS) {
        v = s / fmaxf(Z, 1e-30f);
        v = v > 0.f ? v : __expf(v) - 1.f;
    } else {
        v = -INFINITY;
    }
    float mx = v;
    #pragma unroll
    for (int off = 32; off >= 1; off >>= 1) mx = fmaxf(mx, __shfl_xor(mx, off));
    float ex = (lane < NCLASS) ? __expf(v - mx) : 0.f;
    #pragma unroll
    for (int off = 32; off >= 1; off >>= 1) ex += __shfl_xor(ex, off);
    float lse = mx + __logf(ex);
    if (lane < NCLASS) out[(size_t)n * NCLASS + lane] = v - lse;
}

// ---------------------------------------------------------------------------------
extern "C" void kernel_launch(void* const* d_in, const int* in_sizes, int n_in,
                              void* d_out, int out_size, void* d_ws, size_t ws_size,
                              hipStream_t stream) {
    const float* x   = (const float*)d_in[0];
    const int*   adj = (const int*)d_in[1];
    const float* W1  = (const float*)d_in[2];
    const float* a1  = (const float*)d_in[3];
    const float* Wo  = (const float*)d_in[4];
    const float* ao  = (const float*)d_in[5];

    float* ws    = (float*)d_ws;
    float* h1    = ws;                        // 2,097,152
    float* F1    = h1 + 2097152;              // 32,768
    float* F2    = F1 + 32768;                // 32,768
    float* Wh2   = F2 + 32768;                // 163,840
    float* F1o   = Wh2 + 163840;              // 4,096
    float* F2o   = F1o + 4096;                // 4,096
    float* pz    = F2o + 4096;                // 65,536 (16*4096, k5a)
    float* pz1   = pz + 65536;                // 65,536 (2*8*4096, k3)
    u16*   Wh1T  = (u16*)(pz1 + 65536);       // 2,097,152 u16
    u16*   Wh2T  = Wh1T + 2097152;            // 163,840 u16
    float* R     = (float*)(Wh2T + 163840);   // 4,194,304 f32 shared region
    u16*   xb    = (u16*)R;                   // kcx -> k1m (dies before k3)
    u16*   W1b   = xb + 2097152;              // kcw -> k1m (dies before k3)
    float* pacc1 = R;                         // k3 -> k3b (2*8*4096*64)
    float* pacc  = R;                         // k5a -> k5b (16*4096*40)

    const int* adj0 = adj;                    // layer-2 mask
    const int* adj1 = adj + (size_t)N * N;    // layer-1 mask

    hipLaunchKernelGGL(kcx,       dim3(1024),     dim3(256), 0, stream, x, xb);
    hipLaunchKernelGGL(kcw,       dim3(8, 8),     dim3(256), 0, stream, W1, W1b);
    hipLaunchKernelGGL(k1m_gemm1, dim3(64, 8),    dim3(256), 0, stream, xb, W1b, Wh1T);
    hipLaunchKernelGGL(k2_f12,    dim3(128),      dim3(256), 0, stream, Wh1T, a1, F1, F2);
    hipLaunchKernelGGL(k3_attn1,  dim3(64, 8, 2), dim3(256), 0, stream, adj1, Wh1T, F1, F2, pacc1, pz1);
    hipLaunchKernelGGL(k3b_norm,  dim3(8192),     dim3(256), 0, stream, pacc1, pz1, h1);
    hipLaunchKernelGGL(k4_gemm2,  dim3(1024),     dim3(256), 0, stream, h1, Wo, Wh2);
    hipLaunchKernelGGL(k4b_fo,    dim3(16),       dim3(256), 0, stream, Wh2, ao, F1o, F2o, Wh2T);
    hipLaunchKernelGGL(k5a_attn2, dim3(64, 16),   dim3(256), 0, stream, adj0, Wh2T, F1o, F2o, pacc, pz);
    hipLaunchKernelGGL(k5b_final, dim3(1024),     dim3(256), 0, stream, pacc, pz, (float*)d_out);
}